// Round 10
// baseline (214.428 us; speedup 1.0000x reference)
//
#include <hip/hip_runtime.h>
#include <math.h>

// ---------------------------------------------------------------------------
// 2-layer GCN (PyG GCNConv) on MI355X — tiled-partition CSR + MLP-deep gather.
// GEMM1 via bf16 MFMA (no LDS). Non-temporal (nt) hints on all stream-once
// traffic (srcSorted, src/dst, pairBuf re-reads, x, out) so the per-XCD L2
// retains the random-gather working sets (g1b 6.4MB, g2b 1.6MB).
// out[i] = logsoftmax( dinv[i]*(g2[i] + sum_{e:dst=i} g2[src_e]) + b2 )
// g2 = dinv*( relu( dinv*(g1[i]+sum g1[src]) + b1 ) @ W2 ), g1 = (x@W1)*dinv
// ---------------------------------------------------------------------------

#define F_IN   128
#define F_HID  32
#define F_OUT  7
#define TILE   4096
#define BSH    9              // 512 nodes per bucket
#define BNODES 512

typedef __attribute__((ext_vector_type(8))) short bf16x8;
typedef __attribute__((ext_vector_type(4))) float f32x4;

__device__ __forceinline__ float bf2f(unsigned short u) {
    return __uint_as_float(((unsigned int)u) << 16);
}
__device__ __forceinline__ unsigned short f2bf(float f) {
    unsigned int u = __float_as_uint(f);
    u += 0x7FFF + ((u >> 16) & 1);   // round-to-nearest-even
    return (unsigned short)(u >> 16);
}
__device__ __forceinline__ unsigned int pack2(unsigned short lo, unsigned short hi) {
    return (unsigned int)lo | ((unsigned int)hi << 16);
}
#define NTL(p) __builtin_nontemporal_load(p)

// Pass A: per-tile histogram over NB buckets. counts is tile-major [NT][NB].
__global__ void k_tileHist(const int* __restrict__ dst, int E, int NB,
                           int* __restrict__ counts) {
    __shared__ int h[BNODES];
    int tile = blockIdx.x, t = threadIdx.x;
    for (int i = t; i < NB; i += 256) h[i] = 0;
    __syncthreads();
    int base = tile * TILE;
    int lim = base + TILE; if (lim > E) lim = E;
    for (int i = base + t; i < lim; i += 256) atomicAdd(&h[NTL(&dst[i]) >> BSH], 1);
    __syncthreads();
    for (int i = t; i < NB; i += 256) counts[tile * NB + i] = h[i];
}

// Exclusive scan of counts in BUCKET-MAJOR order (idx = b*NT + t).
__global__ void k_scanA(const int* __restrict__ counts, int NSCAN, int NB, int NT,
                        int* __restrict__ bsum) {
    __shared__ int s[1024];
    int t = threadIdx.x;
    int idx = blockIdx.x * 1024 + t;
    int v = 0;
    if (idx < NSCAN) { int b = idx / NT, tt = idx - b * NT; v = counts[tt * NB + b]; }
    s[t] = v;
    __syncthreads();
    for (int off = 512; off > 0; off >>= 1) {
        if (t < off) s[t] += s[t + off];
        __syncthreads();
    }
    if (t == 0) bsum[blockIdx.x] = s[0];
}

__global__ void k_scanB(int* __restrict__ bsum, int nb) {  // nb <= 1024
    __shared__ int s[1024];
    int t = threadIdx.x;
    int v = (t < nb) ? bsum[t] : 0;
    s[t] = v;
    __syncthreads();
    for (int off = 1; off < 1024; off <<= 1) {
        int a = (t >= off) ? s[t - off] : 0;
        __syncthreads();
        s[t] += a;
        __syncthreads();
    }
    if (t < nb) bsum[t] = s[t] - v;
}

__global__ void k_scanC(const int* __restrict__ counts, int NSCAN, int NB, int NT,
                        const int* __restrict__ bsum, int* __restrict__ tileOffset) {
    __shared__ int s[1024];
    int t = threadIdx.x;
    int idx = blockIdx.x * 1024 + t;
    int v = 0;
    if (idx < NSCAN) { int b = idx / NT, tt = idx - b * NT; v = counts[tt * NB + b]; }
    s[t] = v;
    __syncthreads();
    for (int off = 1; off < 1024; off <<= 1) {
        int a = (t >= off) ? s[t - off] : 0;
        __syncthreads();
        s[t] += a;
        __syncthreads();
    }
    if (idx < NSCAN) tileOffset[idx] = bsum[blockIdx.x] + s[t] - v;  // bucket-major linear
}

// Pass B: scatter packed (local9|src17) into per-(tile,bucket) contiguous runs.
// Tile index is XCD-chunk swizzled (bijective): consecutive tiles -> same XCD.
__global__ void k_tileFill(const int* __restrict__ src, const int* __restrict__ dst,
                           int E, int NB, int NT, const int* __restrict__ tileOffset,
                           int* __restrict__ pairBuf) {
    __shared__ int lcur[BNODES];
    int bid = blockIdx.x;
    int xcd = bid & 7;
    int idx = bid >> 3;
    int q = NT >> 3, r = NT & 7;
    int tile = (xcd < r ? xcd * (q + 1) : r * (q + 1) + (xcd - r) * q) + idx;
    int t = threadIdx.x;
    for (int i = t; i < NB; i += 256) lcur[i] = tileOffset[i * NT + tile];
    __syncthreads();
    int base = tile * TILE;
    int lim = base + TILE; if (lim > E) lim = E;
    for (int i = base + t; i < lim; i += 256) {
        int s = NTL(&src[i]), d = NTL(&dst[i]);
        int b = d >> BSH;
        int pos = atomicAdd(&lcur[b], 1);              // LDS cursor, run is tile-private
        pairBuf[pos] = ((d & (BNODES - 1)) << 17) | s; // src < 2^17
    }
}

// Pass C: per-bucket CSR finish — degi/cursor/dinv + srcSorted placement.
__global__ void k_bucketCSR(const int* __restrict__ pairBuf, const int* __restrict__ tileOffset,
                            int NT, int NB, int E, int n,
                            int* __restrict__ degi, int* __restrict__ cursor,
                            float* __restrict__ dinv, int* __restrict__ srcSorted) {
    __shared__ int cnt[BNODES];
    __shared__ int pref[BNODES];
    int b = blockIdx.x, t = threadIdx.x;
    cnt[t] = 0;
    __syncthreads();
    int bs = tileOffset[b * NT];
    int be = (b + 1 < NB) ? tileOffset[(b + 1) * NT] : E;
    for (int j = bs + t; j < be; j += BNODES) atomicAdd(&cnt[NTL(&pairBuf[j]) >> 17], 1);
    __syncthreads();
    int v = cnt[t];
    pref[t] = v;
    __syncthreads();
    for (int off = 1; off < BNODES; off <<= 1) {
        int a = (t >= off) ? pref[t - off] : 0;
        __syncthreads();
        pref[t] += a;
        __syncthreads();
    }
    int ex = pref[t] - v;                 // exclusive prefix within bucket
    int node = (b << BSH) + t;
    if (node < n) {
        degi[node]   = v;
        cursor[node] = bs + ex;
        dinv[node]   = rsqrtf((float)v + 1.0f);  // +1 self-loop
    }
    __syncthreads();
    cnt[t] = bs + ex;                     // reuse as placement cursors
    __syncthreads();
    for (int j = bs + t; j < be; j += BNODES) {
        int p = NTL(&pairBuf[j]);
        int pos = atomicAdd(&cnt[p >> 17], 1);
        srcSorted[pos] = p & 0x1FFFF;     // writes confined to bucket's ~65KB region
    }
}

// Precompute bf16 B-fragments of W1 for mfma_f32_16x16x32_bf16.
__global__ void k_wT(const float* __restrict__ W1, unsigned short* __restrict__ Wfrag) {
    int t = threadIdx.x;
    for (int i = 0; i < 16; ++i) {
        int idx = t + i * 256;            // 4096 elements
        int j = idx & 7;
        int l = (idx >> 3) & 63;
        int f = idx >> 9;                 // 0..7
        int nt = f >> 2, ks = f & 3;
        int k = ks * 32 + ((l >> 4) << 3) + j;
        int col = nt * 16 + (l & 15);
        Wfrag[idx] = f2bf(W1[k * F_HID + col]);
    }
}

// GEMM1 via MFMA: wave = 16 rows x 32 cols, K=128 in 4 steps. No LDS.
__global__ void k_gemm1(const float* __restrict__ x, const unsigned short* __restrict__ Wfrag,
                        const float* __restrict__ dinv, unsigned short* __restrict__ g1b,
                        int n) {
    int wave = threadIdx.x >> 6;          // 0..3
    int lane = threadIdx.x & 63;
    int row0 = (blockIdx.x * 4 + wave) * 16;
    if (row0 >= n) return;                // n % 16 == 0, so full tiles only
    bf16x8 bfr[2][4];
    #pragma unroll
    for (int nt = 0; nt < 2; ++nt)
        #pragma unroll
        for (int ks = 0; ks < 4; ++ks)
            bfr[nt][ks] = *(const bf16x8*)&Wfrag[(((nt << 2) + ks) * 64 + lane) << 3];
    int arow = row0 + (lane & 15);
    const float* xr = x + (size_t)arow * F_IN + ((lane >> 4) << 3);
    f32x4 acc0 = {0.f, 0.f, 0.f, 0.f};
    f32x4 acc1 = {0.f, 0.f, 0.f, 0.f};
    #pragma unroll
    for (int ks = 0; ks < 4; ++ks) {
        f32x4 lo = NTL((const f32x4*)(xr + ks * 32));
        f32x4 hi = NTL((const f32x4*)(xr + ks * 32 + 4));
        bf16x8 a;
        a[0] = (short)f2bf(lo[0]); a[1] = (short)f2bf(lo[1]);
        a[2] = (short)f2bf(lo[2]); a[3] = (short)f2bf(lo[3]);
        a[4] = (short)f2bf(hi[0]); a[5] = (short)f2bf(hi[1]);
        a[6] = (short)f2bf(hi[2]); a[7] = (short)f2bf(hi[3]);
        acc0 = __builtin_amdgcn_mfma_f32_16x16x32_bf16(a, bfr[0][ks], acc0, 0, 0, 0);
        acc1 = __builtin_amdgcn_mfma_f32_16x16x32_bf16(a, bfr[1][ks], acc1, 0, 0, 0);
    }
    int col = lane & 15;
    #pragma unroll
    for (int rr = 0; rr < 4; ++rr) {
        int orow = row0 + ((lane >> 4) << 2) + rr;
        float di = dinv[orow];
        g1b[(size_t)orow * F_HID + col]      = f2bf(acc0[rr] * di);
        g1b[(size_t)orow * F_HID + col + 16] = f2bf(acc1[rr] * di);
    }
}

// Gather conv1 + ReLU + tiny GEMM2 fused.
// 8 lanes/node (lane c owns 4 bf16 feats as ushort4), 32 nodes/block.
// 4-edge unroll, fp32 accumulators; srcSorted read nt (stream), g1 cached.
__global__ void k_gather1l2(const ushort4* __restrict__ g1v, const int* __restrict__ srcSorted,
                            const int* __restrict__ cursor, const int* __restrict__ degi,
                            const float* __restrict__ dinv, const float* __restrict__ b1,
                            const float* __restrict__ W2, unsigned int* __restrict__ g2b,
                            int n) {
    int t = threadIdx.x;
    int c = t & 7;
    int node = blockIdx.x * 32 + (t >> 3);
    if (node >= n) return;
    int start = cursor[node];
    int end = start + degi[node];
    ushort4 sv = g1v[node * 8 + c];   // self-loop init
    float ax = bf2f(sv.x), ay = bf2f(sv.y), az = bf2f(sv.z), aw = bf2f(sv.w);
    float bx = 0.f, by = 0.f, bz = 0.f, bw = 0.f;
    float cx = 0.f, cy = 0.f, cz = 0.f, cw = 0.f;
    float dx = 0.f, dy = 0.f, dz = 0.f, dw = 0.f;
    int j = start;
    for (; j + 4 <= end; j += 4) {
        int s0 = NTL(&srcSorted[j]);
        int s1 = NTL(&srcSorted[j + 1]);
        int s2 = NTL(&srcSorted[j + 2]);
        int s3 = NTL(&srcSorted[j + 3]);
        ushort4 v0 = g1v[s0 * 8 + c];
        ushort4 v1 = g1v[s1 * 8 + c];
        ushort4 v2 = g1v[s2 * 8 + c];
        ushort4 v3 = g1v[s3 * 8 + c];
        ax += bf2f(v0.x); ay += bf2f(v0.y); az += bf2f(v0.z); aw += bf2f(v0.w);
        bx += bf2f(v1.x); by += bf2f(v1.y); bz += bf2f(v1.z); bw += bf2f(v1.w);
        cx += bf2f(v2.x); cy += bf2f(v2.y); cz += bf2f(v2.z); cw += bf2f(v2.w);
        dx += bf2f(v3.x); dy += bf2f(v3.y); dz += bf2f(v3.z); dw += bf2f(v3.w);
    }
    for (; j < end; ++j) {
        ushort4 v0 = g1v[NTL(&srcSorted[j]) * 8 + c];
        ax += bf2f(v0.x); ay += bf2f(v0.y); az += bf2f(v0.z); aw += bf2f(v0.w);
    }
    float accx = (ax + bx) + (cx + dx);
    float accy = (ay + by) + (cy + dy);
    float accz = (az + bz) + (cz + dz);
    float accw = (aw + bw) + (cw + dw);
    float di = dinv[node];
    float4 b4 = ((const float4*)b1)[c];
    float hx = fmaxf(di * accx + b4.x, 0.f);
    float hy = fmaxf(di * accy + b4.y, 0.f);
    float hz = fmaxf(di * accz + b4.z, 0.f);
    float hw = fmaxf(di * accw + b4.w, 0.f);
    float p[F_OUT];
    #pragma unroll
    for (int k = 0; k < F_OUT; ++k) {
        p[k] = hx * W2[(4 * c + 0) * F_OUT + k]
             + hy * W2[(4 * c + 1) * F_OUT + k]
             + hz * W2[(4 * c + 2) * F_OUT + k]
             + hw * W2[(4 * c + 3) * F_OUT + k];
    }
    #pragma unroll
    for (int m = 1; m < 8; m <<= 1) {
        #pragma unroll
        for (int k = 0; k < F_OUT; ++k) p[k] += __shfl_xor(p[k], m, 64);
    }
    if (c == 0) {
        uint4 q;
        q.x = pack2(f2bf(di * p[0]), f2bf(di * p[1]));
        q.y = pack2(f2bf(di * p[2]), f2bf(di * p[3]));
        q.z = pack2(f2bf(di * p[4]), f2bf(di * p[5]));
        q.w = pack2(f2bf(di * p[6]), 0);
        *(uint4*)&g2b[node * 4] = q;      // 16B bf16 row (8 slots, last = 0)
    }
}

// Gather conv2 + bias + log-softmax fused. 8 lanes/node, 4-edge unroll.
// g2 rows bf16 (1.6MB, L2-resident); srcSorted nt; out store nt.
__global__ void k_gather2final(const unsigned short* __restrict__ g2b,
                               const int* __restrict__ srcSorted,
                               const int* __restrict__ cursor, const int* __restrict__ degi,
                               const float* __restrict__ dinv, const float* __restrict__ b2,
                               float* __restrict__ out, int n) {
    int t = threadIdx.x;
    int c = t & 7;
    int node = blockIdx.x * 32 + (t >> 3);
    if (node >= n) return;
    int start = cursor[node];
    int end = start + degi[node];
    float a0 = bf2f(g2b[node * 8 + c]);   // self-loop init (pad col = 0)
    float a1 = 0.f, a2 = 0.f, a3 = 0.f;
    int j = start;
    for (; j + 4 <= end; j += 4) {
        int s0 = NTL(&srcSorted[j]);
        int s1 = NTL(&srcSorted[j + 1]);
        int s2 = NTL(&srcSorted[j + 2]);
        int s3 = NTL(&srcSorted[j + 3]);
        a0 += bf2f(g2b[s0 * 8 + c]);
        a1 += bf2f(g2b[s1 * 8 + c]);
        a2 += bf2f(g2b[s2 * 8 + c]);
        a3 += bf2f(g2b[s3 * 8 + c]);
    }
    for (; j < end; ++j) a0 += bf2f(g2b[NTL(&srcSorted[j]) * 8 + c]);
    float acc = (a0 + a1) + (a2 + a3);
    float v = dinv[node] * acc + ((c < F_OUT) ? b2[c] : -1e30f);
    float m = v;
    #pragma unroll
    for (int msk = 1; msk < 8; msk <<= 1) m = fmaxf(m, __shfl_xor(m, msk, 64));
    float ex = __expf(v - m);
    float ssum = ex;
    #pragma unroll
    for (int msk = 1; msk < 8; msk <<= 1) ssum += __shfl_xor(ssum, msk, 64);
    float ls = __logf(ssum) + m;
    if (c < F_OUT) __builtin_nontemporal_store(v - ls, &out[node * F_OUT + c]);
}

extern "C" void kernel_launch(void* const* d_in, const int* in_sizes, int n_in,
                              void* d_out, int out_size, void* d_ws, size_t ws_size,
                              hipStream_t stream) {
    const float* x  = (const float*)d_in[0];
    const int*   ei = (const int*)d_in[1];
    const float* W1 = (const float*)d_in[2];
    const float* b1 = (const float*)d_in[3];
    const float* W2 = (const float*)d_in[4];
    const float* b2 = (const float*)d_in[5];
    float* out = (float*)d_out;

    int n = in_sizes[0] / F_IN;            // 100000
    int E = in_sizes[1] / 2;               // 3200000
    const int* src = ei;
    const int* dst = ei + E;
    int NB = (n + BNODES - 1) >> BSH;      // 196 buckets
    int NT = (E + TILE - 1) / TILE;        // 782 tiles
    int NSCAN = NB * NT;                   // 153272
    int nsb = (NSCAN + 1023) / 1024;       // 150 scan blocks

    // workspace layout (g1b aliases pairBuf: pairBuf dead after k_bucketCSR)
    int*            degi       = (int*)d_ws;                  // [n]
    int*            cursor     = degi + n;                    // [n]
    float*          dinv       = (float*)(cursor + n);        // [n]
    int*            srcSorted  = (int*)(dinv + n);            // [E]
    int*            pairBuf    = srcSorted + E;               // [E] (reused as g1b)
    unsigned short* g1b        = (unsigned short*)pairBuf;    // [n*32] bf16
    unsigned short* g2b        = (unsigned short*)(pairBuf + E); // [n*8] bf16
    int*            counts     = (int*)(g2b + (size_t)n * 8); // [NSCAN] tile-major
    int*            tileOffset = counts + NSCAN;              // [NSCAN] bucket-major
    int*            bsum       = tileOffset + NSCAN;          // [nsb]
    unsigned short* Wfrag      = (unsigned short*)(bsum + ((nsb + 3) & ~3)); // [4096] bf16

    k_wT<<<1, 256, 0, stream>>>(W1, Wfrag);
    k_tileHist<<<NT, 256, 0, stream>>>(dst, E, NB, counts);
    k_scanA<<<nsb, 1024, 0, stream>>>(counts, NSCAN, NB, NT, bsum);
    k_scanB<<<1, 1024, 0, stream>>>(bsum, nsb);
    k_scanC<<<nsb, 1024, 0, stream>>>(counts, NSCAN, NB, NT, bsum, tileOffset);
    k_tileFill<<<NT, 256, 0, stream>>>(src, dst, E, NB, NT, tileOffset, pairBuf);
    k_bucketCSR<<<NB, BNODES, 0, stream>>>(pairBuf, tileOffset, NT, NB, E, n,
                                           degi, cursor, dinv, srcSorted);
    k_gemm1<<<(n + 63) / 64, 256, 0, stream>>>(x, Wfrag, dinv, g1b, n);
    k_gather1l2<<<(n + 31) / 32, 256, 0, stream>>>((const ushort4*)g1b, srcSorted, cursor, degi,
                                                   dinv, b1, W2, (unsigned int*)g2b, n);
    k_gather2final<<<(n + 31) / 32, 256, 0, stream>>>(g2b, srcSorted, cursor, degi, dinv, b2, out, n);
}

// Round 11
// 177.981 us; speedup vs baseline: 1.2048x; 1.2048x over previous
//
#include <hip/hip_runtime.h>
#include <math.h>

// ---------------------------------------------------------------------------
// 2-layer GCN (PyG GCNConv) on MI355X — tiled-partition CSR + MLP-deep gather.
// GEMM1 via bf16 MFMA (no LDS). bucketCSR is single-pass (bucket pairs staged
// in LDS) and emits QUARTER-ORDERED per-node edge lists (sub-sorted by src
// quartile) so co-resident gather blocks sweep g1b one 1.6MB quartile at a
// time (L2-resident phase working set). nt hints only on true single-touch
// streams (src/dst, pairBuf single read, x, out).
// out[i] = logsoftmax( dinv[i]*(g2[i] + sum_{e:dst=i} g2[src_e]) + b2 )
// g2 = dinv*( relu( dinv*(g1[i]+sum g1[src]) + b1 ) @ W2 ), g1 = (x@W1)*dinv
// ---------------------------------------------------------------------------

#define F_IN   128
#define F_HID  32
#define F_OUT  7
#define TILE   4096
#define BSH    9              // 512 nodes per bucket
#define BNODES 512
#define PCAP   20480          // LDS pair capacity (avg bucket 16326, 4sigma ~16900)

typedef __attribute__((ext_vector_type(8))) short bf16x8;
typedef __attribute__((ext_vector_type(4))) float f32x4;

__device__ __forceinline__ float bf2f(unsigned short u) {
    return __uint_as_float(((unsigned int)u) << 16);
}
__device__ __forceinline__ unsigned short f2bf(float f) {
    unsigned int u = __float_as_uint(f);
    u += 0x7FFF + ((u >> 16) & 1);   // round-to-nearest-even
    return (unsigned short)(u >> 16);
}
__device__ __forceinline__ unsigned int pack2(unsigned short lo, unsigned short hi) {
    return (unsigned int)lo | ((unsigned int)hi << 16);
}
#define NTL(p) __builtin_nontemporal_load(p)

// Pass A: per-tile histogram over NB buckets. counts is tile-major [NT][NB].
__global__ void k_tileHist(const int* __restrict__ dst, int E, int NB,
                           int* __restrict__ counts) {
    __shared__ int h[BNODES];
    int tile = blockIdx.x, t = threadIdx.x;
    for (int i = t; i < NB; i += 256) h[i] = 0;
    __syncthreads();
    int base = tile * TILE;
    int lim = base + TILE; if (lim > E) lim = E;
    for (int i = base + t; i < lim; i += 256) atomicAdd(&h[NTL(&dst[i]) >> BSH], 1);
    __syncthreads();
    for (int i = t; i < NB; i += 256) counts[tile * NB + i] = h[i];
}

// Exclusive scan of counts in BUCKET-MAJOR order (idx = b*NT + t).
__global__ void k_scanA(const int* __restrict__ counts, int NSCAN, int NB, int NT,
                        int* __restrict__ bsum) {
    __shared__ int s[1024];
    int t = threadIdx.x;
    int idx = blockIdx.x * 1024 + t;
    int v = 0;
    if (idx < NSCAN) { int b = idx / NT, tt = idx - b * NT; v = counts[tt * NB + b]; }
    s[t] = v;
    __syncthreads();
    for (int off = 512; off > 0; off >>= 1) {
        if (t < off) s[t] += s[t + off];
        __syncthreads();
    }
    if (t == 0) bsum[blockIdx.x] = s[0];
}

__global__ void k_scanB(int* __restrict__ bsum, int nb) {  // nb <= 1024
    __shared__ int s[1024];
    int t = threadIdx.x;
    int v = (t < nb) ? bsum[t] : 0;
    s[t] = v;
    __syncthreads();
    for (int off = 1; off < 1024; off <<= 1) {
        int a = (t >= off) ? s[t - off] : 0;
        __syncthreads();
        s[t] += a;
        __syncthreads();
    }
    if (t < nb) bsum[t] = s[t] - v;
}

__global__ void k_scanC(const int* __restrict__ counts, int NSCAN, int NB, int NT,
                        const int* __restrict__ bsum, int* __restrict__ tileOffset) {
    __shared__ int s[1024];
    int t = threadIdx.x;
    int idx = blockIdx.x * 1024 + t;
    int v = 0;
    if (idx < NSCAN) { int b = idx / NT, tt = idx - b * NT; v = counts[tt * NB + b]; }
    s[t] = v;
    __syncthreads();
    for (int off = 1; off < 1024; off <<= 1) {
        int a = (t >= off) ? s[t - off] : 0;
        __syncthreads();
        s[t] += a;
        __syncthreads();
    }
    if (idx < NSCAN) tileOffset[idx] = bsum[blockIdx.x] + s[t] - v;  // bucket-major linear
}

// Pass B: scatter packed (local9|src17) into per-(tile,bucket) contiguous runs.
// Tile index is XCD-chunk swizzled (bijective): consecutive tiles -> same XCD.
__global__ void k_tileFill(const int* __restrict__ src, const int* __restrict__ dst,
                           int E, int NB, int NT, const int* __restrict__ tileOffset,
                           int* __restrict__ pairBuf) {
    __shared__ int lcur[BNODES];
    int bid = blockIdx.x;
    int xcd = bid & 7;
    int idx = bid >> 3;
    int q = NT >> 3, r = NT & 7;
    int tile = (xcd < r ? xcd * (q + 1) : r * (q + 1) + (xcd - r) * q) + idx;
    int t = threadIdx.x;
    for (int i = t; i < NB; i += 256) lcur[i] = tileOffset[i * NT + tile];
    __syncthreads();
    int base = tile * TILE;
    int lim = base + TILE; if (lim > E) lim = E;
    for (int i = base + t; i < lim; i += 256) {
        int s = NTL(&src[i]), d = NTL(&dst[i]);
        int b = d >> BSH;
        int pos = atomicAdd(&lcur[b], 1);              // LDS cursor, run is tile-private
        pairBuf[pos] = ((d & (BNODES - 1)) << 17) | s; // src < 2^17
    }
}

// Pass C: single-pass per-bucket CSR finish. Bucket pairs staged in LDS
// (pairBuf read ONCE, nt). Per-(node,quarter) histogram + 2048-entry scan ->
// degi/cursor/dinv + quarter-ordered srcSorted placement.
__global__ __launch_bounds__(512)
void k_bucketCSR(const int* __restrict__ pairBuf, const int* __restrict__ tileOffset,
                 int NT, int NB, int E, int n,
                 int* __restrict__ degi, int* __restrict__ cursor,
                 float* __restrict__ dinv, int* __restrict__ srcSorted) {
    __shared__ int pairs[PCAP];      // 80 KB
    __shared__ int cntq[BNODES * 4]; // 8 KB  (node-local<<2 | quarter)
    __shared__ int pref[BNODES * 4]; // 8 KB
    __shared__ int s512[512];        // 2 KB
    int b = blockIdx.x, t = threadIdx.x;
    int base = t << 2;
    #pragma unroll
    for (int i = 0; i < 4; ++i) cntq[base + i] = 0;
    __syncthreads();
    int bs = tileOffset[b * NT];
    int be = (b + 1 < NB) ? tileOffset[(b + 1) * NT] : E;
    int sz = be - bs;
    int th1 = n >> 2, th2 = n >> 1, th3 = (n >> 2) + (n >> 1);
    // pass 1: global -> LDS stage + (node,quarter) histogram
    for (int j = bs + t; j < be; j += 512) {
        int p = NTL(&pairBuf[j]);
        int idx = j - bs;
        if (idx < PCAP) pairs[idx] = p;
        int s = p & 0x1FFFF;
        int q = (s >= th1) + (s >= th2) + (s >= th3);
        atomicAdd(&cntq[((p >> 17) << 2) | q], 1);
    }
    __syncthreads();
    // exclusive scan over 2048 entries (thread t owns entries 4t..4t+3)
    int v0 = cntq[base], v1 = cntq[base + 1], v2 = cntq[base + 2], v3 = cntq[base + 3];
    int sum = v0 + v1 + v2 + v3;
    s512[t] = sum;
    __syncthreads();
    for (int off = 1; off < 512; off <<= 1) {
        int a = (t >= off) ? s512[t - off] : 0;
        __syncthreads();
        s512[t] += a;
        __syncthreads();
    }
    int ex = s512[t] - sum;          // exclusive prefix at entry 4t
    pref[base]     = bs + ex;
    pref[base + 1] = bs + ex + v0;
    pref[base + 2] = bs + ex + v0 + v1;
    pref[base + 3] = bs + ex + v0 + v1 + v2;
    int node = (b << BSH) + t;       // node-local index == t
    if (node < n) {
        degi[node]   = sum;
        cursor[node] = bs + ex;
        dinv[node]   = rsqrtf((float)sum + 1.0f);  // +1 self-loop
    }
    __syncthreads();
    // pass 2: placement from LDS (global fallback for overflow tail)
    for (int idx = t; idx < sz; idx += 512) {
        int p = (idx < PCAP) ? pairs[idx] : NTL(&pairBuf[bs + idx]);
        int s = p & 0x1FFFF;
        int q = (s >= th1) + (s >= th2) + (s >= th3);
        int pos = atomicAdd(&pref[((p >> 17) << 2) | q], 1);
        srcSorted[pos] = s;          // writes confined to bucket's ~65KB region
    }
}

// Precompute bf16 B-fragments of W1 for mfma_f32_16x16x32_bf16.
__global__ void k_wT(const float* __restrict__ W1, unsigned short* __restrict__ Wfrag) {
    int t = threadIdx.x;
    for (int i = 0; i < 16; ++i) {
        int idx = t + i * 256;            // 4096 elements
        int j = idx & 7;
        int l = (idx >> 3) & 63;
        int f = idx >> 9;                 // 0..7
        int nt = f >> 2, ks = f & 3;
        int k = ks * 32 + ((l >> 4) << 3) + j;
        int col = nt * 16 + (l & 15);
        Wfrag[idx] = f2bf(W1[k * F_HID + col]);
    }
}

// GEMM1 via MFMA: wave = 16 rows x 32 cols, K=128 in 4 steps. No LDS.
__global__ void k_gemm1(const float* __restrict__ x, const unsigned short* __restrict__ Wfrag,
                        const float* __restrict__ dinv, unsigned short* __restrict__ g1b,
                        int n) {
    int wave = threadIdx.x >> 6;          // 0..3
    int lane = threadIdx.x & 63;
    int row0 = (blockIdx.x * 4 + wave) * 16;
    if (row0 >= n) return;                // n % 16 == 0, so full tiles only
    bf16x8 bfr[2][4];
    #pragma unroll
    for (int nt = 0; nt < 2; ++nt)
        #pragma unroll
        for (int ks = 0; ks < 4; ++ks)
            bfr[nt][ks] = *(const bf16x8*)&Wfrag[(((nt << 2) + ks) * 64 + lane) << 3];
    int arow = row0 + (lane & 15);
    const float* xr = x + (size_t)arow * F_IN + ((lane >> 4) << 3);
    f32x4 acc0 = {0.f, 0.f, 0.f, 0.f};
    f32x4 acc1 = {0.f, 0.f, 0.f, 0.f};
    #pragma unroll
    for (int ks = 0; ks < 4; ++ks) {
        f32x4 lo = NTL((const f32x4*)(xr + ks * 32));
        f32x4 hi = NTL((const f32x4*)(xr + ks * 32 + 4));
        bf16x8 a;
        a[0] = (short)f2bf(lo[0]); a[1] = (short)f2bf(lo[1]);
        a[2] = (short)f2bf(lo[2]); a[3] = (short)f2bf(lo[3]);
        a[4] = (short)f2bf(hi[0]); a[5] = (short)f2bf(hi[1]);
        a[6] = (short)f2bf(hi[2]); a[7] = (short)f2bf(hi[3]);
        acc0 = __builtin_amdgcn_mfma_f32_16x16x32_bf16(a, bfr[0][ks], acc0, 0, 0, 0);
        acc1 = __builtin_amdgcn_mfma_f32_16x16x32_bf16(a, bfr[1][ks], acc1, 0, 0, 0);
    }
    int col = lane & 15;
    #pragma unroll
    for (int rr = 0; rr < 4; ++rr) {
        int orow = row0 + ((lane >> 4) << 2) + rr;
        float di = dinv[orow];
        g1b[(size_t)orow * F_HID + col]      = f2bf(acc0[rr] * di);
        g1b[(size_t)orow * F_HID + col + 16] = f2bf(acc1[rr] * di);
    }
}

// Gather conv1 + ReLU + tiny GEMM2 fused.
// 8 lanes/node (lane c owns 4 bf16 feats as ushort4), 32 nodes/block.
// 4-edge unroll, fp32 accumulators. srcSorted plain-cached (line reused
// across iterations). Quarter-ordered lists give phase-local g1b access.
__global__ void k_gather1l2(const ushort4* __restrict__ g1v, const int* __restrict__ srcSorted,
                            const int* __restrict__ cursor, const int* __restrict__ degi,
                            const float* __restrict__ dinv, const float* __restrict__ b1,
                            const float* __restrict__ W2, unsigned int* __restrict__ g2b,
                            int n) {
    int t = threadIdx.x;
    int c = t & 7;
    int node = blockIdx.x * 32 + (t >> 3);
    if (node >= n) return;
    int start = cursor[node];
    int end = start + degi[node];
    ushort4 sv = g1v[node * 8 + c];   // self-loop init
    float ax = bf2f(sv.x), ay = bf2f(sv.y), az = bf2f(sv.z), aw = bf2f(sv.w);
    float bx = 0.f, by = 0.f, bz = 0.f, bw = 0.f;
    float cx = 0.f, cy = 0.f, cz = 0.f, cw = 0.f;
    float dx = 0.f, dy = 0.f, dz = 0.f, dw = 0.f;
    int j = start;
    for (; j + 4 <= end; j += 4) {
        int s0 = srcSorted[j];
        int s1 = srcSorted[j + 1];
        int s2 = srcSorted[j + 2];
        int s3 = srcSorted[j + 3];
        ushort4 v0 = g1v[s0 * 8 + c];
        ushort4 v1 = g1v[s1 * 8 + c];
        ushort4 v2 = g1v[s2 * 8 + c];
        ushort4 v3 = g1v[s3 * 8 + c];
        ax += bf2f(v0.x); ay += bf2f(v0.y); az += bf2f(v0.z); aw += bf2f(v0.w);
        bx += bf2f(v1.x); by += bf2f(v1.y); bz += bf2f(v1.z); bw += bf2f(v1.w);
        cx += bf2f(v2.x); cy += bf2f(v2.y); cz += bf2f(v2.z); cw += bf2f(v2.w);
        dx += bf2f(v3.x); dy += bf2f(v3.y); dz += bf2f(v3.z); dw += bf2f(v3.w);
    }
    for (; j < end; ++j) {
        ushort4 v0 = g1v[srcSorted[j] * 8 + c];
        ax += bf2f(v0.x); ay += bf2f(v0.y); az += bf2f(v0.z); aw += bf2f(v0.w);
    }
    float accx = (ax + bx) + (cx + dx);
    float accy = (ay + by) + (cy + dy);
    float accz = (az + bz) + (cz + dz);
    float accw = (aw + bw) + (cw + dw);
    float di = dinv[node];
    float4 b4 = ((const float4*)b1)[c];
    float hx = fmaxf(di * accx + b4.x, 0.f);
    float hy = fmaxf(di * accy + b4.y, 0.f);
    float hz = fmaxf(di * accz + b4.z, 0.f);
    float hw = fmaxf(di * accw + b4.w, 0.f);
    float p[F_OUT];
    #pragma unroll
    for (int k = 0; k < F_OUT; ++k) {
        p[k] = hx * W2[(4 * c + 0) * F_OUT + k]
             + hy * W2[(4 * c + 1) * F_OUT + k]
             + hz * W2[(4 * c + 2) * F_OUT + k]
             + hw * W2[(4 * c + 3) * F_OUT + k];
    }
    #pragma unroll
    for (int m = 1; m < 8; m <<= 1) {
        #pragma unroll
        for (int k = 0; k < F_OUT; ++k) p[k] += __shfl_xor(p[k], m, 64);
    }
    if (c == 0) {
        uint4 q;
        q.x = pack2(f2bf(di * p[0]), f2bf(di * p[1]));
        q.y = pack2(f2bf(di * p[2]), f2bf(di * p[3]));
        q.z = pack2(f2bf(di * p[4]), f2bf(di * p[5]));
        q.w = pack2(f2bf(di * p[6]), 0);
        *(uint4*)&g2b[node * 4] = q;      // 16B bf16 row (8 slots, last = 0)
    }
}

// Gather conv2 + bias + log-softmax fused. 8 lanes/node, 4-edge unroll.
// g2 rows bf16 (1.6MB, L2-resident); out store nt.
__global__ void k_gather2final(const unsigned short* __restrict__ g2b,
                               const int* __restrict__ srcSorted,
                               const int* __restrict__ cursor, const int* __restrict__ degi,
                               const float* __restrict__ dinv, const float* __restrict__ b2,
                               float* __restrict__ out, int n) {
    int t = threadIdx.x;
    int c = t & 7;
    int node = blockIdx.x * 32 + (t >> 3);
    if (node >= n) return;
    int start = cursor[node];
    int end = start + degi[node];
    float a0 = bf2f(g2b[node * 8 + c]);   // self-loop init (pad col = 0)
    float a1 = 0.f, a2 = 0.f, a3 = 0.f;
    int j = start;
    for (; j + 4 <= end; j += 4) {
        int s0 = srcSorted[j];
        int s1 = srcSorted[j + 1];
        int s2 = srcSorted[j + 2];
        int s3 = srcSorted[j + 3];
        a0 += bf2f(g2b[s0 * 8 + c]);
        a1 += bf2f(g2b[s1 * 8 + c]);
        a2 += bf2f(g2b[s2 * 8 + c]);
        a3 += bf2f(g2b[s3 * 8 + c]);
    }
    for (; j < end; ++j) a0 += bf2f(g2b[srcSorted[j] * 8 + c]);
    float acc = (a0 + a1) + (a2 + a3);
    float v = dinv[node] * acc + ((c < F_OUT) ? b2[c] : -1e30f);
    float m = v;
    #pragma unroll
    for (int msk = 1; msk < 8; msk <<= 1) m = fmaxf(m, __shfl_xor(m, msk, 64));
    float ex = __expf(v - m);
    float ssum = ex;
    #pragma unroll
    for (int msk = 1; msk < 8; msk <<= 1) ssum += __shfl_xor(ssum, msk, 64);
    float ls = __logf(ssum) + m;
    if (c < F_OUT) __builtin_nontemporal_store(v - ls, &out[node * F_OUT + c]);
}

extern "C" void kernel_launch(void* const* d_in, const int* in_sizes, int n_in,
                              void* d_out, int out_size, void* d_ws, size_t ws_size,
                              hipStream_t stream) {
    const float* x  = (const float*)d_in[0];
    const int*   ei = (const int*)d_in[1];
    const float* W1 = (const float*)d_in[2];
    const float* b1 = (const float*)d_in[3];
    const float* W2 = (const float*)d_in[4];
    const float* b2 = (const float*)d_in[5];
    float* out = (float*)d_out;

    int n = in_sizes[0] / F_IN;            // 100000
    int E = in_sizes[1] / 2;               // 3200000
    const int* src = ei;
    const int* dst = ei + E;
    int NB = (n + BNODES - 1) >> BSH;      // 196 buckets
    int NT = (E + TILE - 1) / TILE;        // 782 tiles
    int NSCAN = NB * NT;                   // 153272
    int nsb = (NSCAN + 1023) / 1024;       // 150 scan blocks

    // workspace layout (g1b aliases pairBuf: pairBuf dead after k_bucketCSR)
    int*            degi       = (int*)d_ws;                  // [n]
    int*            cursor     = degi + n;                    // [n]
    float*          dinv       = (float*)(cursor + n);        // [n]
    int*            srcSorted  = (int*)(dinv + n);            // [E]
    int*            pairBuf    = srcSorted + E;               // [E] (reused as g1b)
    unsigned short* g1b        = (unsigned short*)pairBuf;    // [n*32] bf16
    unsigned short* g2b        = (unsigned short*)(pairBuf + E); // [n*8] bf16
    int*            counts     = (int*)(g2b + (size_t)n * 8); // [NSCAN] tile-major
    int*            tileOffset = counts + NSCAN;              // [NSCAN] bucket-major
    int*            bsum       = tileOffset + NSCAN;          // [nsb]
    unsigned short* Wfrag      = (unsigned short*)(bsum + ((nsb + 3) & ~3)); // [4096] bf16

    k_wT<<<1, 256, 0, stream>>>(W1, Wfrag);
    k_tileHist<<<NT, 256, 0, stream>>>(dst, E, NB, counts);
    k_scanA<<<nsb, 1024, 0, stream>>>(counts, NSCAN, NB, NT, bsum);
    k_scanB<<<1, 1024, 0, stream>>>(bsum, nsb);
    k_scanC<<<nsb, 1024, 0, stream>>>(counts, NSCAN, NB, NT, bsum, tileOffset);
    k_tileFill<<<NT, 256, 0, stream>>>(src, dst, E, NB, NT, tileOffset, pairBuf);
    k_bucketCSR<<<NB, 512, 0, stream>>>(pairBuf, tileOffset, NT, NB, E, n,
                                        degi, cursor, dinv, srcSorted);
    k_gemm1<<<(n + 63) / 64, 256, 0, stream>>>(x, Wfrag, dinv, g1b, n);
    k_gather1l2<<<(n + 31) / 32, 256, 0, stream>>>((const ushort4*)g1b, srcSorted, cursor, degi,
                                                   dinv, b1, W2, (unsigned int*)g2b, n);
    k_gather2final<<<(n + 31) / 32, 256, 0, stream>>>(g2b, srcSorted, cursor, degi, dinv, b2, out, n);
}

// Round 12
// 157.472 us; speedup vs baseline: 1.3617x; 1.1302x over previous
//
#include <hip/hip_runtime.h>
#include <math.h>

// ---------------------------------------------------------------------------
// 2-layer GCN (PyG GCNConv) on MI355X — tiled-partition CSR + MLP-deep gather.
// GEMM1 via bf16 MFMA (no LDS). bucketCSR: 256-node buckets, quarter-ordered
// per-node lists, output staged in LDS then dumped with coalesced stores
// (fixes 8x partial-sector write amplification of scattered 4B stores).
// out[i] = logsoftmax( dinv[i]*(g2[i] + sum_{e:dst=i} g2[src_e]) + b2 )
// g2 = dinv*( relu( dinv*(g1[i]+sum g1[src]) + b1 ) @ W2 ), g1 = (x@W1)*dinv
// ---------------------------------------------------------------------------

#define F_IN   128
#define F_HID  32
#define F_OUT  7
#define TILE   4096
#define BSH    8              // 256 nodes per bucket
#define BNODES 256
#define HSZ    512            // LDS histogram capacity (>= NB = 391)
#define PCAP   10240          // LDS sorted-output capacity (avg bucket 8184, +22sigma)

typedef __attribute__((ext_vector_type(8))) short bf16x8;
typedef __attribute__((ext_vector_type(4))) float f32x4;

__device__ __forceinline__ float bf2f(unsigned short u) {
    return __uint_as_float(((unsigned int)u) << 16);
}
__device__ __forceinline__ unsigned short f2bf(float f) {
    unsigned int u = __float_as_uint(f);
    u += 0x7FFF + ((u >> 16) & 1);   // round-to-nearest-even
    return (unsigned short)(u >> 16);
}
__device__ __forceinline__ unsigned int pack2(unsigned short lo, unsigned short hi) {
    return (unsigned int)lo | ((unsigned int)hi << 16);
}
#define NTL(p) __builtin_nontemporal_load(p)

// Pass A: per-tile histogram over NB buckets. counts is tile-major [NT][NB].
__global__ void k_tileHist(const int* __restrict__ dst, int E, int NB,
                           int* __restrict__ counts) {
    __shared__ int h[HSZ];
    int tile = blockIdx.x, t = threadIdx.x;
    for (int i = t; i < NB; i += 256) h[i] = 0;
    __syncthreads();
    int base = tile * TILE;
    int lim = base + TILE; if (lim > E) lim = E;
    for (int i = base + t; i < lim; i += 256) atomicAdd(&h[NTL(&dst[i]) >> BSH], 1);
    __syncthreads();
    for (int i = t; i < NB; i += 256) counts[tile * NB + i] = h[i];
}

// Exclusive scan of counts in BUCKET-MAJOR order (idx = b*NT + t).
__global__ void k_scanA(const int* __restrict__ counts, int NSCAN, int NB, int NT,
                        int* __restrict__ bsum) {
    __shared__ int s[1024];
    int t = threadIdx.x;
    int idx = blockIdx.x * 1024 + t;
    int v = 0;
    if (idx < NSCAN) { int b = idx / NT, tt = idx - b * NT; v = counts[tt * NB + b]; }
    s[t] = v;
    __syncthreads();
    for (int off = 512; off > 0; off >>= 1) {
        if (t < off) s[t] += s[t + off];
        __syncthreads();
    }
    if (t == 0) bsum[blockIdx.x] = s[0];
}

__global__ void k_scanB(int* __restrict__ bsum, int nb) {  // nb <= 1024
    __shared__ int s[1024];
    int t = threadIdx.x;
    int v = (t < nb) ? bsum[t] : 0;
    s[t] = v;
    __syncthreads();
    for (int off = 1; off < 1024; off <<= 1) {
        int a = (t >= off) ? s[t - off] : 0;
        __syncthreads();
        s[t] += a;
        __syncthreads();
    }
    if (t < nb) bsum[t] = s[t] - v;
}

__global__ void k_scanC(const int* __restrict__ counts, int NSCAN, int NB, int NT,
                        const int* __restrict__ bsum, int* __restrict__ tileOffset) {
    __shared__ int s[1024];
    int t = threadIdx.x;
    int idx = blockIdx.x * 1024 + t;
    int v = 0;
    if (idx < NSCAN) { int b = idx / NT, tt = idx - b * NT; v = counts[tt * NB + b]; }
    s[t] = v;
    __syncthreads();
    for (int off = 1; off < 1024; off <<= 1) {
        int a = (t >= off) ? s[t - off] : 0;
        __syncthreads();
        s[t] += a;
        __syncthreads();
    }
    if (idx < NSCAN) tileOffset[idx] = bsum[blockIdx.x] + s[t] - v;  // bucket-major linear
}

// Pass B: scatter packed (local8|src17) into per-(tile,bucket) contiguous runs.
// Tile index is XCD-chunk swizzled (bijective): consecutive tiles -> same XCD.
__global__ void k_tileFill(const int* __restrict__ src, const int* __restrict__ dst,
                           int E, int NB, int NT, const int* __restrict__ tileOffset,
                           int* __restrict__ pairBuf) {
    __shared__ int lcur[HSZ];
    int bid = blockIdx.x;
    int xcd = bid & 7;
    int idx = bid >> 3;
    int q = NT >> 3, r = NT & 7;
    int tile = (xcd < r ? xcd * (q + 1) : r * (q + 1) + (xcd - r) * q) + idx;
    int t = threadIdx.x;
    for (int i = t; i < NB; i += 256) lcur[i] = tileOffset[i * NT + tile];
    __syncthreads();
    int base = tile * TILE;
    int lim = base + TILE; if (lim > E) lim = E;
    for (int i = base + t; i < lim; i += 256) {
        int s = NTL(&src[i]), d = NTL(&dst[i]);
        int b = d >> BSH;
        int pos = atomicAdd(&lcur[b], 1);              // LDS cursor, run is tile-private
        pairBuf[pos] = ((d & (BNODES - 1)) << 17) | s; // src < 2^17
    }
}

// Pass C: per-bucket CSR finish. pairBuf read twice (2nd pass L2-hit).
// Quarter-ordered placement into LDS outb, then coalesced dump to srcSorted.
__global__ __launch_bounds__(512)
void k_bucketCSR(const int* __restrict__ pairBuf, const int* __restrict__ tileOffset,
                 int NT, int NB, int E, int n,
                 int* __restrict__ degi, int* __restrict__ cursor,
                 float* __restrict__ dinv, int* __restrict__ srcSorted) {
    __shared__ int outb[PCAP];           // 40 KB sorted output staging
    __shared__ int cntq[BNODES * 4];     // 4 KB  (node-local<<2 | quarter)
    __shared__ int pref[BNODES * 4];     // 4 KB  relative cursors
    __shared__ int sred[BNODES];         // 1 KB
    int b = blockIdx.x, t = threadIdx.x;
    for (int i = t; i < BNODES * 4; i += 512) cntq[i] = 0;
    __syncthreads();
    int bs = tileOffset[b * NT];
    int be = (b + 1 < NB) ? tileOffset[(b + 1) * NT] : E;
    int sz = be - bs;
    int th1 = n >> 2, th2 = n >> 1, th3 = (n >> 2) + (n >> 1);
    // pass 1: histogram (plain cached read; lines stay in L2 for pass 2)
    for (int j = bs + t; j < be; j += 512) {
        int p = pairBuf[j];
        int s = p & 0x1FFFF;
        int q = (s >= th1) + (s >= th2) + (s >= th3);
        atomicAdd(&cntq[((p >> 17) << 2) | q], 1);
    }
    __syncthreads();
    // exclusive scan over 1024 entries (threads 0..255 own 4 each)
    int v0 = 0, v1 = 0, v2 = 0, v3 = 0, sum = 0, base = 0;
    if (t < BNODES) {
        base = t << 2;
        v0 = cntq[base]; v1 = cntq[base + 1]; v2 = cntq[base + 2]; v3 = cntq[base + 3];
        sum = v0 + v1 + v2 + v3;
        sred[t] = sum;
    }
    __syncthreads();
    for (int off = 1; off < BNODES; off <<= 1) {
        int a = (t < BNODES && t >= off) ? sred[t - off] : 0;
        __syncthreads();
        if (t < BNODES) sred[t] += a;
        __syncthreads();
    }
    if (t < BNODES) {
        int ex = sred[t] - sum;          // relative exclusive prefix
        pref[base]     = ex;
        pref[base + 1] = ex + v0;
        pref[base + 2] = ex + v0 + v1;
        pref[base + 3] = ex + v0 + v1 + v2;
        int node = (b << BSH) + t;
        if (node < n) {
            degi[node]   = sum;
            cursor[node] = bs + ex;
            dinv[node]   = rsqrtf((float)sum + 1.0f);  // +1 self-loop
        }
    }
    __syncthreads();
    // pass 2: placement into LDS (relative positions); global fallback tail
    for (int j = bs + t; j < be; j += 512) {
        int p = pairBuf[j];
        int s = p & 0x1FFFF;
        int q = (s >= th1) + (s >= th2) + (s >= th3);
        int pos = atomicAdd(&pref[((p >> 17) << 2) | q], 1);
        if (pos < PCAP) outb[pos] = s;
        else            srcSorted[bs + pos] = s;
    }
    __syncthreads();
    // pass 3: coalesced dump LDS -> global
    int lim = sz < PCAP ? sz : PCAP;
    for (int idx = t; idx < lim; idx += 512) srcSorted[bs + idx] = outb[idx];
}

// Precompute bf16 B-fragments of W1 for mfma_f32_16x16x32_bf16.
__global__ void k_wT(const float* __restrict__ W1, unsigned short* __restrict__ Wfrag) {
    int t = threadIdx.x;
    for (int i = 0; i < 16; ++i) {
        int idx = t + i * 256;            // 4096 elements
        int j = idx & 7;
        int l = (idx >> 3) & 63;
        int f = idx >> 9;                 // 0..7
        int nt = f >> 2, ks = f & 3;
        int k = ks * 32 + ((l >> 4) << 3) + j;
        int col = nt * 16 + (l & 15);
        Wfrag[idx] = f2bf(W1[k * F_HID + col]);
    }
}

// GEMM1 via MFMA: wave = 16 rows x 32 cols, K=128 in 4 steps. No LDS.
__global__ void k_gemm1(const float* __restrict__ x, const unsigned short* __restrict__ Wfrag,
                        const float* __restrict__ dinv, unsigned short* __restrict__ g1b,
                        int n) {
    int wave = threadIdx.x >> 6;          // 0..3
    int lane = threadIdx.x & 63;
    int row0 = (blockIdx.x * 4 + wave) * 16;
    if (row0 >= n) return;                // n % 16 == 0, so full tiles only
    bf16x8 bfr[2][4];
    #pragma unroll
    for (int nt = 0; nt < 2; ++nt)
        #pragma unroll
        for (int ks = 0; ks < 4; ++ks)
            bfr[nt][ks] = *(const bf16x8*)&Wfrag[(((nt << 2) + ks) * 64 + lane) << 3];
    int arow = row0 + (lane & 15);
    const float* xr = x + (size_t)arow * F_IN + ((lane >> 4) << 3);
    f32x4 acc0 = {0.f, 0.f, 0.f, 0.f};
    f32x4 acc1 = {0.f, 0.f, 0.f, 0.f};
    #pragma unroll
    for (int ks = 0; ks < 4; ++ks) {
        f32x4 lo = NTL((const f32x4*)(xr + ks * 32));
        f32x4 hi = NTL((const f32x4*)(xr + ks * 32 + 4));
        bf16x8 a;
        a[0] = (short)f2bf(lo[0]); a[1] = (short)f2bf(lo[1]);
        a[2] = (short)f2bf(lo[2]); a[3] = (short)f2bf(lo[3]);
        a[4] = (short)f2bf(hi[0]); a[5] = (short)f2bf(hi[1]);
        a[6] = (short)f2bf(hi[2]); a[7] = (short)f2bf(hi[3]);
        acc0 = __builtin_amdgcn_mfma_f32_16x16x32_bf16(a, bfr[0][ks], acc0, 0, 0, 0);
        acc1 = __builtin_amdgcn_mfma_f32_16x16x32_bf16(a, bfr[1][ks], acc1, 0, 0, 0);
    }
    int col = lane & 15;
    #pragma unroll
    for (int rr = 0; rr < 4; ++rr) {
        int orow = row0 + ((lane >> 4) << 2) + rr;
        float di = dinv[orow];
        g1b[(size_t)orow * F_HID + col]      = f2bf(acc0[rr] * di);
        g1b[(size_t)orow * F_HID + col + 16] = f2bf(acc1[rr] * di);
    }
}

// Gather conv1 + ReLU + tiny GEMM2 fused.
// 8 lanes/node (lane c owns 4 bf16 feats as ushort4), 32 nodes/block.
// 4-edge unroll, fp32 accumulators. Quarter-ordered lists -> phase-local g1b.
__global__ void k_gather1l2(const ushort4* __restrict__ g1v, const int* __restrict__ srcSorted,
                            const int* __restrict__ cursor, const int* __restrict__ degi,
                            const float* __restrict__ dinv, const float* __restrict__ b1,
                            const float* __restrict__ W2, unsigned int* __restrict__ g2b,
                            int n) {
    int t = threadIdx.x;
    int c = t & 7;
    int node = blockIdx.x * 32 + (t >> 3);
    if (node >= n) return;
    int start = cursor[node];
    int end = start + degi[node];
    ushort4 sv = g1v[node * 8 + c];   // self-loop init
    float ax = bf2f(sv.x), ay = bf2f(sv.y), az = bf2f(sv.z), aw = bf2f(sv.w);
    float bx = 0.f, by = 0.f, bz = 0.f, bw = 0.f;
    float cx = 0.f, cy = 0.f, cz = 0.f, cw = 0.f;
    float dx = 0.f, dy = 0.f, dz = 0.f, dw = 0.f;
    int j = start;
    for (; j + 4 <= end; j += 4) {
        int s0 = srcSorted[j];
        int s1 = srcSorted[j + 1];
        int s2 = srcSorted[j + 2];
        int s3 = srcSorted[j + 3];
        ushort4 v0 = g1v[s0 * 8 + c];
        ushort4 v1 = g1v[s1 * 8 + c];
        ushort4 v2 = g1v[s2 * 8 + c];
        ushort4 v3 = g1v[s3 * 8 + c];
        ax += bf2f(v0.x); ay += bf2f(v0.y); az += bf2f(v0.z); aw += bf2f(v0.w);
        bx += bf2f(v1.x); by += bf2f(v1.y); bz += bf2f(v1.z); bw += bf2f(v1.w);
        cx += bf2f(v2.x); cy += bf2f(v2.y); cz += bf2f(v2.z); cw += bf2f(v2.w);
        dx += bf2f(v3.x); dy += bf2f(v3.y); dz += bf2f(v3.z); dw += bf2f(v3.w);
    }
    for (; j < end; ++j) {
        ushort4 v0 = g1v[srcSorted[j] * 8 + c];
        ax += bf2f(v0.x); ay += bf2f(v0.y); az += bf2f(v0.z); aw += bf2f(v0.w);
    }
    float accx = (ax + bx) + (cx + dx);
    float accy = (ay + by) + (cy + dy);
    float accz = (az + bz) + (cz + dz);
    float accw = (aw + bw) + (cw + dw);
    float di = dinv[node];
    float4 b4 = ((const float4*)b1)[c];
    float hx = fmaxf(di * accx + b4.x, 0.f);
    float hy = fmaxf(di * accy + b4.y, 0.f);
    float hz = fmaxf(di * accz + b4.z, 0.f);
    float hw = fmaxf(di * accw + b4.w, 0.f);
    float p[F_OUT];
    #pragma unroll
    for (int k = 0; k < F_OUT; ++k) {
        p[k] = hx * W2[(4 * c + 0) * F_OUT + k]
             + hy * W2[(4 * c + 1) * F_OUT + k]
             + hz * W2[(4 * c + 2) * F_OUT + k]
             + hw * W2[(4 * c + 3) * F_OUT + k];
    }
    #pragma unroll
    for (int m = 1; m < 8; m <<= 1) {
        #pragma unroll
        for (int k = 0; k < F_OUT; ++k) p[k] += __shfl_xor(p[k], m, 64);
    }
    if (c == 0) {
        uint4 q;
        q.x = pack2(f2bf(di * p[0]), f2bf(di * p[1]));
        q.y = pack2(f2bf(di * p[2]), f2bf(di * p[3]));
        q.z = pack2(f2bf(di * p[4]), f2bf(di * p[5]));
        q.w = pack2(f2bf(di * p[6]), 0);
        *(uint4*)&g2b[node * 4] = q;      // 16B bf16 row (8 slots, last = 0)
    }
}

// Gather conv2 + bias + log-softmax fused. 8 lanes/node, 4-edge unroll.
// g2 rows bf16 (1.6MB, L2-resident); out store nt.
__global__ void k_gather2final(const unsigned short* __restrict__ g2b,
                               const int* __restrict__ srcSorted,
                               const int* __restrict__ cursor, const int* __restrict__ degi,
                               const float* __restrict__ dinv, const float* __restrict__ b2,
                               float* __restrict__ out, int n) {
    int t = threadIdx.x;
    int c = t & 7;
    int node = blockIdx.x * 32 + (t >> 3);
    if (node >= n) return;
    int start = cursor[node];
    int end = start + degi[node];
    float a0 = bf2f(g2b[node * 8 + c]);   // self-loop init (pad col = 0)
    float a1 = 0.f, a2 = 0.f, a3 = 0.f;
    int j = start;
    for (; j + 4 <= end; j += 4) {
        int s0 = srcSorted[j];
        int s1 = srcSorted[j + 1];
        int s2 = srcSorted[j + 2];
        int s3 = srcSorted[j + 3];
        a0 += bf2f(g2b[s0 * 8 + c]);
        a1 += bf2f(g2b[s1 * 8 + c]);
        a2 += bf2f(g2b[s2 * 8 + c]);
        a3 += bf2f(g2b[s3 * 8 + c]);
    }
    for (; j < end; ++j) a0 += bf2f(g2b[srcSorted[j] * 8 + c]);
    float acc = (a0 + a1) + (a2 + a3);
    float v = dinv[node] * acc + ((c < F_OUT) ? b2[c] : -1e30f);
    float m = v;
    #pragma unroll
    for (int msk = 1; msk < 8; msk <<= 1) m = fmaxf(m, __shfl_xor(m, msk, 64));
    float ex = __expf(v - m);
    float ssum = ex;
    #pragma unroll
    for (int msk = 1; msk < 8; msk <<= 1) ssum += __shfl_xor(ssum, msk, 64);
    float ls = __logf(ssum) + m;
    if (c < F_OUT) __builtin_nontemporal_store(v - ls, &out[node * F_OUT + c]);
}

extern "C" void kernel_launch(void* const* d_in, const int* in_sizes, int n_in,
                              void* d_out, int out_size, void* d_ws, size_t ws_size,
                              hipStream_t stream) {
    const float* x  = (const float*)d_in[0];
    const int*   ei = (const int*)d_in[1];
    const float* W1 = (const float*)d_in[2];
    const float* b1 = (const float*)d_in[3];
    const float* W2 = (const float*)d_in[4];
    const float* b2 = (const float*)d_in[5];
    float* out = (float*)d_out;

    int n = in_sizes[0] / F_IN;            // 100000
    int E = in_sizes[1] / 2;               // 3200000
    const int* src = ei;
    const int* dst = ei + E;
    int NB = (n + BNODES - 1) >> BSH;      // 391 buckets
    int NT = (E + TILE - 1) / TILE;        // 782 tiles
    int NSCAN = NB * NT;                   // 305762
    int nsb = (NSCAN + 1023) / 1024;       // 299 scan blocks (<=1024)

    // workspace layout (g1b aliases pairBuf: pairBuf dead after k_bucketCSR)
    int*            degi       = (int*)d_ws;                  // [n]
    int*            cursor     = degi + n;                    // [n]
    float*          dinv       = (float*)(cursor + n);        // [n]
    int*            srcSorted  = (int*)(dinv + n);            // [E]
    int*            pairBuf    = srcSorted + E;               // [E] (reused as g1b)
    unsigned short* g1b        = (unsigned short*)pairBuf;    // [n*32] bf16
    unsigned short* g2b        = (unsigned short*)(pairBuf + E); // [n*8] bf16
    int*            counts     = (int*)(g2b + (size_t)n * 8); // [NSCAN] tile-major
    int*            tileOffset = counts + NSCAN;              // [NSCAN] bucket-major
    int*            bsum       = tileOffset + NSCAN;          // [nsb]
    unsigned short* Wfrag      = (unsigned short*)(bsum + ((nsb + 3) & ~3)); // [4096] bf16

    k_wT<<<1, 256, 0, stream>>>(W1, Wfrag);
    k_tileHist<<<NT, 256, 0, stream>>>(dst, E, NB, counts);
    k_scanA<<<nsb, 1024, 0, stream>>>(counts, NSCAN, NB, NT, bsum);
    k_scanB<<<1, 1024, 0, stream>>>(bsum, nsb);
    k_scanC<<<nsb, 1024, 0, stream>>>(counts, NSCAN, NB, NT, bsum, tileOffset);
    k_tileFill<<<NT, 256, 0, stream>>>(src, dst, E, NB, NT, tileOffset, pairBuf);
    k_bucketCSR<<<NB, 512, 0, stream>>>(pairBuf, tileOffset, NT, NB, E, n,
                                        degi, cursor, dinv, srcSorted);
    k_gemm1<<<(n + 63) / 64, 256, 0, stream>>>(x, Wfrag, dinv, g1b, n);
    k_gather1l2<<<(n + 31) / 32, 256, 0, stream>>>((const ushort4*)g1b, srcSorted, cursor, degi,
                                                   dinv, b1, W2, (unsigned int*)g2b, n);
    k_gather2final<<<(n + 31) / 32, 256, 0, stream>>>(g2b, srcSorted, cursor, degi, dinv, b2, out, n);
}

// Round 13
// 143.031 us; speedup vs baseline: 1.4992x; 1.1010x over previous
//
#include <hip/hip_runtime.h>
#include <math.h>

// ---------------------------------------------------------------------------
// 2-layer GCN (PyG GCNConv) on MI355X — tiled-partition CSR + MLP-deep gather.
// GEMM1 via bf16 MFMA. bucketCSR: 256-node buckets, quarter-ordered lists,
// LDS-staged coalesced output. This round: TILE=8192 (half the scan work),
// i32x4 nt edge loads in tileHist/tileFill, gather2 repacked to 4 lanes/node
// with uint (2xbf16) loads.
// out[i] = logsoftmax( dinv[i]*(g2[i] + sum_{e:dst=i} g2[src_e]) + b2 )
// g2 = dinv*( relu( dinv*(g1[i]+sum g1[src]) + b1 ) @ W2 ), g1 = (x@W1)*dinv
// ---------------------------------------------------------------------------

#define F_IN   128
#define F_HID  32
#define F_OUT  7
#define TILE   8192
#define BSH    8              // 256 nodes per bucket
#define BNODES 256
#define HSZ    512            // LDS histogram capacity (>= NB = 391)
#define PCAP   10240          // LDS sorted-output capacity (avg bucket 8184)

typedef __attribute__((ext_vector_type(8))) short bf16x8;
typedef __attribute__((ext_vector_type(4))) float f32x4;
typedef __attribute__((ext_vector_type(4))) int   i32x4;

__device__ __forceinline__ float bf2f(unsigned short u) {
    return __uint_as_float(((unsigned int)u) << 16);
}
__device__ __forceinline__ unsigned short f2bf(float f) {
    unsigned int u = __float_as_uint(f);
    u += 0x7FFF + ((u >> 16) & 1);   // round-to-nearest-even
    return (unsigned short)(u >> 16);
}
__device__ __forceinline__ unsigned int pack2(unsigned short lo, unsigned short hi) {
    return (unsigned int)lo | ((unsigned int)hi << 16);
}
#define NTL(p) __builtin_nontemporal_load(p)

// Pass A: per-tile histogram over NB buckets. counts is tile-major [NT][NB].
__global__ __launch_bounds__(512)
void k_tileHist(const int* __restrict__ dst, int E, int NB, int* __restrict__ counts) {
    __shared__ int h[HSZ];
    int tile = blockIdx.x, t = threadIdx.x;
    for (int i = t; i < NB; i += 512) h[i] = 0;
    __syncthreads();
    int base = tile * TILE;
    int lim = base + TILE; if (lim > E) lim = E;
    int n4 = (lim - base) >> 2;            // base and E divisible by 4
    const i32x4* d4 = (const i32x4*)(dst + base);
    for (int i = t; i < n4; i += 512) {
        i32x4 d = NTL(&d4[i]);
        atomicAdd(&h[d[0] >> BSH], 1);
        atomicAdd(&h[d[1] >> BSH], 1);
        atomicAdd(&h[d[2] >> BSH], 1);
        atomicAdd(&h[d[3] >> BSH], 1);
    }
    __syncthreads();
    for (int i = t; i < NB; i += 512) counts[tile * NB + i] = h[i];
}

// Exclusive scan of counts in BUCKET-MAJOR order (idx = b*NT + t).
__global__ void k_scanA(const int* __restrict__ counts, int NSCAN, int NB, int NT,
                        int* __restrict__ bsum) {
    __shared__ int s[1024];
    int t = threadIdx.x;
    int idx = blockIdx.x * 1024 + t;
    int v = 0;
    if (idx < NSCAN) { int b = idx / NT, tt = idx - b * NT; v = counts[tt * NB + b]; }
    s[t] = v;
    __syncthreads();
    for (int off = 512; off > 0; off >>= 1) {
        if (t < off) s[t] += s[t + off];
        __syncthreads();
    }
    if (t == 0) bsum[blockIdx.x] = s[0];
}

__global__ void k_scanB(int* __restrict__ bsum, int nb) {  // nb <= 1024
    __shared__ int s[1024];
    int t = threadIdx.x;
    int v = (t < nb) ? bsum[t] : 0;
    s[t] = v;
    __syncthreads();
    for (int off = 1; off < 1024; off <<= 1) {
        int a = (t >= off) ? s[t - off] : 0;
        __syncthreads();
        s[t] += a;
        __syncthreads();
    }
    if (t < nb) bsum[t] = s[t] - v;
}

__global__ void k_scanC(const int* __restrict__ counts, int NSCAN, int NB, int NT,
                        const int* __restrict__ bsum, int* __restrict__ tileOffset) {
    __shared__ int s[1024];
    int t = threadIdx.x;
    int idx = blockIdx.x * 1024 + t;
    int v = 0;
    if (idx < NSCAN) { int b = idx / NT, tt = idx - b * NT; v = counts[tt * NB + b]; }
    s[t] = v;
    __syncthreads();
    for (int off = 1; off < 1024; off <<= 1) {
        int a = (t >= off) ? s[t - off] : 0;
        __syncthreads();
        s[t] += a;
        __syncthreads();
    }
    if (idx < NSCAN) tileOffset[idx] = bsum[blockIdx.x] + s[t] - v;  // bucket-major linear
}

// Pass B: scatter packed (local8|src17) into per-(tile,bucket) contiguous runs.
// Tile index is XCD-chunk swizzled (bijective): consecutive tiles -> same XCD.
__global__ __launch_bounds__(512)
void k_tileFill(const int* __restrict__ src, const int* __restrict__ dst,
                int E, int NB, int NT, const int* __restrict__ tileOffset,
                int* __restrict__ pairBuf) {
    __shared__ int lcur[HSZ];
    int bid = blockIdx.x;
    int xcd = bid & 7;
    int idx = bid >> 3;
    int q = NT >> 3, r = NT & 7;
    int tile = (xcd < r ? xcd * (q + 1) : r * (q + 1) + (xcd - r) * q) + idx;
    int t = threadIdx.x;
    for (int i = t; i < NB; i += 512) lcur[i] = tileOffset[i * NT + tile];
    __syncthreads();
    int base = tile * TILE;
    int lim = base + TILE; if (lim > E) lim = E;
    int n4 = (lim - base) >> 2;
    const i32x4* s4 = (const i32x4*)(src + base);
    const i32x4* d4 = (const i32x4*)(dst + base);
    for (int i = t; i < n4; i += 512) {
        i32x4 s = NTL(&s4[i]);
        i32x4 d = NTL(&d4[i]);
        #pragma unroll
        for (int k = 0; k < 4; ++k) {
            int b = d[k] >> BSH;
            int pos = atomicAdd(&lcur[b], 1);                 // LDS cursor
            pairBuf[pos] = ((d[k] & (BNODES - 1)) << 17) | s[k]; // src < 2^17
        }
    }
}

// Pass C: per-bucket CSR finish. pairBuf read twice (2nd pass L2-hit).
// Quarter-ordered placement into LDS outb, then coalesced dump to srcSorted.
__global__ __launch_bounds__(512)
void k_bucketCSR(const int* __restrict__ pairBuf, const int* __restrict__ tileOffset,
                 int NT, int NB, int E, int n,
                 int* __restrict__ degi, int* __restrict__ cursor,
                 float* __restrict__ dinv, int* __restrict__ srcSorted) {
    __shared__ int outb[PCAP];           // 40 KB sorted output staging
    __shared__ int cntq[BNODES * 4];     // 4 KB  (node-local<<2 | quarter)
    __shared__ int pref[BNODES * 4];     // 4 KB  relative cursors
    __shared__ int sred[BNODES];         // 1 KB
    int b = blockIdx.x, t = threadIdx.x;
    for (int i = t; i < BNODES * 4; i += 512) cntq[i] = 0;
    __syncthreads();
    int bs = tileOffset[b * NT];
    int be = (b + 1 < NB) ? tileOffset[(b + 1) * NT] : E;
    int sz = be - bs;
    int th1 = n >> 2, th2 = n >> 1, th3 = (n >> 2) + (n >> 1);
    // pass 1: histogram (plain cached read; lines stay in L2 for pass 2)
    for (int j = bs + t; j < be; j += 512) {
        int p = pairBuf[j];
        int s = p & 0x1FFFF;
        int q = (s >= th1) + (s >= th2) + (s >= th3);
        atomicAdd(&cntq[((p >> 17) << 2) | q], 1);
    }
    __syncthreads();
    // exclusive scan over 1024 entries (threads 0..255 own 4 each)
    int v0 = 0, v1 = 0, v2 = 0, v3 = 0, sum = 0, base = 0;
    if (t < BNODES) {
        base = t << 2;
        v0 = cntq[base]; v1 = cntq[base + 1]; v2 = cntq[base + 2]; v3 = cntq[base + 3];
        sum = v0 + v1 + v2 + v3;
        sred[t] = sum;
    }
    __syncthreads();
    for (int off = 1; off < BNODES; off <<= 1) {
        int a = (t < BNODES && t >= off) ? sred[t - off] : 0;
        __syncthreads();
        if (t < BNODES) sred[t] += a;
        __syncthreads();
    }
    if (t < BNODES) {
        int ex = sred[t] - sum;          // relative exclusive prefix
        pref[base]     = ex;
        pref[base + 1] = ex + v0;
        pref[base + 2] = ex + v0 + v1;
        pref[base + 3] = ex + v0 + v1 + v2;
        int node = (b << BSH) + t;
        if (node < n) {
            degi[node]   = sum;
            cursor[node] = bs + ex;
            dinv[node]   = rsqrtf((float)sum + 1.0f);  // +1 self-loop
        }
    }
    __syncthreads();
    // pass 2: placement into LDS (relative positions); global fallback tail
    for (int j = bs + t; j < be; j += 512) {
        int p = pairBuf[j];
        int s = p & 0x1FFFF;
        int q = (s >= th1) + (s >= th2) + (s >= th3);
        int pos = atomicAdd(&pref[((p >> 17) << 2) | q], 1);
        if (pos < PCAP) outb[pos] = s;
        else            srcSorted[bs + pos] = s;
    }
    __syncthreads();
    // pass 3: coalesced dump LDS -> global
    int lim = sz < PCAP ? sz : PCAP;
    for (int idx = t; idx < lim; idx += 512) srcSorted[bs + idx] = outb[idx];
}

// Precompute bf16 B-fragments of W1 for mfma_f32_16x16x32_bf16.
__global__ void k_wT(const float* __restrict__ W1, unsigned short* __restrict__ Wfrag) {
    int t = threadIdx.x;
    for (int i = 0; i < 16; ++i) {
        int idx = t + i * 256;            // 4096 elements
        int j = idx & 7;
        int l = (idx >> 3) & 63;
        int f = idx >> 9;                 // 0..7
        int nt = f >> 2, ks = f & 3;
        int k = ks * 32 + ((l >> 4) << 3) + j;
        int col = nt * 16 + (l & 15);
        Wfrag[idx] = f2bf(W1[k * F_HID + col]);
    }
}

// GEMM1 via MFMA: wave = 16 rows x 32 cols, K=128 in 4 steps. No LDS.
__global__ void k_gemm1(const float* __restrict__ x, const unsigned short* __restrict__ Wfrag,
                        const float* __restrict__ dinv, unsigned short* __restrict__ g1b,
                        int n) {
    int wave = threadIdx.x >> 6;          // 0..3
    int lane = threadIdx.x & 63;
    int row0 = (blockIdx.x * 4 + wave) * 16;
    if (row0 >= n) return;                // n % 16 == 0, so full tiles only
    bf16x8 bfr[2][4];
    #pragma unroll
    for (int nt = 0; nt < 2; ++nt)
        #pragma unroll
        for (int ks = 0; ks < 4; ++ks)
            bfr[nt][ks] = *(const bf16x8*)&Wfrag[(((nt << 2) + ks) * 64 + lane) << 3];
    int arow = row0 + (lane & 15);
    const float* xr = x + (size_t)arow * F_IN + ((lane >> 4) << 3);
    f32x4 acc0 = {0.f, 0.f, 0.f, 0.f};
    f32x4 acc1 = {0.f, 0.f, 0.f, 0.f};
    #pragma unroll
    for (int ks = 0; ks < 4; ++ks) {
        f32x4 lo = NTL((const f32x4*)(xr + ks * 32));
        f32x4 hi = NTL((const f32x4*)(xr + ks * 32 + 4));
        bf16x8 a;
        a[0] = (short)f2bf(lo[0]); a[1] = (short)f2bf(lo[1]);
        a[2] = (short)f2bf(lo[2]); a[3] = (short)f2bf(lo[3]);
        a[4] = (short)f2bf(hi[0]); a[5] = (short)f2bf(hi[1]);
        a[6] = (short)f2bf(hi[2]); a[7] = (short)f2bf(hi[3]);
        acc0 = __builtin_amdgcn_mfma_f32_16x16x32_bf16(a, bfr[0][ks], acc0, 0, 0, 0);
        acc1 = __builtin_amdgcn_mfma_f32_16x16x32_bf16(a, bfr[1][ks], acc1, 0, 0, 0);
    }
    int col = lane & 15;
    #pragma unroll
    for (int rr = 0; rr < 4; ++rr) {
        int orow = row0 + ((lane >> 4) << 2) + rr;
        float di = dinv[orow];
        g1b[(size_t)orow * F_HID + col]      = f2bf(acc0[rr] * di);
        g1b[(size_t)orow * F_HID + col + 16] = f2bf(acc1[rr] * di);
    }
}

// Gather conv1 + ReLU + tiny GEMM2 fused.
// 8 lanes/node (lane c owns 4 bf16 feats as ushort4), 32 nodes/block.
// 4-edge unroll, fp32 accumulators. Quarter-ordered lists -> phase-local g1b.
__global__ void k_gather1l2(const ushort4* __restrict__ g1v, const int* __restrict__ srcSorted,
                            const int* __restrict__ cursor, const int* __restrict__ degi,
                            const float* __restrict__ dinv, const float* __restrict__ b1,
                            const float* __restrict__ W2, unsigned int* __restrict__ g2b,
                            int n) {
    int t = threadIdx.x;
    int c = t & 7;
    int node = blockIdx.x * 32 + (t >> 3);
    if (node >= n) return;
    int start = cursor[node];
    int end = start + degi[node];
    ushort4 sv = g1v[node * 8 + c];   // self-loop init
    float ax = bf2f(sv.x), ay = bf2f(sv.y), az = bf2f(sv.z), aw = bf2f(sv.w);
    float bx = 0.f, by = 0.f, bz = 0.f, bw = 0.f;
    float cx = 0.f, cy = 0.f, cz = 0.f, cw = 0.f;
    float dx = 0.f, dy = 0.f, dz = 0.f, dw = 0.f;
    int j = start;
    for (; j + 4 <= end; j += 4) {
        int s0 = srcSorted[j];
        int s1 = srcSorted[j + 1];
        int s2 = srcSorted[j + 2];
        int s3 = srcSorted[j + 3];
        ushort4 v0 = g1v[s0 * 8 + c];
        ushort4 v1 = g1v[s1 * 8 + c];
        ushort4 v2 = g1v[s2 * 8 + c];
        ushort4 v3 = g1v[s3 * 8 + c];
        ax += bf2f(v0.x); ay += bf2f(v0.y); az += bf2f(v0.z); aw += bf2f(v0.w);
        bx += bf2f(v1.x); by += bf2f(v1.y); bz += bf2f(v1.z); bw += bf2f(v1.w);
        cx += bf2f(v2.x); cy += bf2f(v2.y); cz += bf2f(v2.z); cw += bf2f(v2.w);
        dx += bf2f(v3.x); dy += bf2f(v3.y); dz += bf2f(v3.z); dw += bf2f(v3.w);
    }
    for (; j < end; ++j) {
        ushort4 v0 = g1v[srcSorted[j] * 8 + c];
        ax += bf2f(v0.x); ay += bf2f(v0.y); az += bf2f(v0.z); aw += bf2f(v0.w);
    }
    float accx = (ax + bx) + (cx + dx);
    float accy = (ay + by) + (cy + dy);
    float accz = (az + bz) + (cz + dz);
    float accw = (aw + bw) + (cw + dw);
    float di = dinv[node];
    float4 b4 = ((const float4*)b1)[c];
    float hx = fmaxf(di * accx + b4.x, 0.f);
    float hy = fmaxf(di * accy + b4.y, 0.f);
    float hz = fmaxf(di * accz + b4.z, 0.f);
    float hw = fmaxf(di * accw + b4.w, 0.f);
    float p[F_OUT];
    #pragma unroll
    for (int k = 0; k < F_OUT; ++k) {
        p[k] = hx * W2[(4 * c + 0) * F_OUT + k]
             + hy * W2[(4 * c + 1) * F_OUT + k]
             + hz * W2[(4 * c + 2) * F_OUT + k]
             + hw * W2[(4 * c + 3) * F_OUT + k];
    }
    #pragma unroll
    for (int m = 1; m < 8; m <<= 1) {
        #pragma unroll
        for (int k = 0; k < F_OUT; ++k) p[k] += __shfl_xor(p[k], m, 64);
    }
    if (c == 0) {
        uint4 q;
        q.x = pack2(f2bf(di * p[0]), f2bf(di * p[1]));
        q.y = pack2(f2bf(di * p[2]), f2bf(di * p[3]));
        q.z = pack2(f2bf(di * p[4]), f2bf(di * p[5]));
        q.w = pack2(f2bf(di * p[6]), 0);
        *(uint4*)&g2b[node * 4] = q;      // 16B bf16 row (8 slots, last = 0)
    }
}

// Gather conv2 + bias + log-softmax fused. 4 lanes/node, uint (2xbf16) loads,
// 4-edge unroll. g2 rows bf16 (1.6MB, L2-resident); out store nt.
__global__ void k_gather2final(const unsigned int* __restrict__ g2u,
                               const int* __restrict__ srcSorted,
                               const int* __restrict__ cursor, const int* __restrict__ degi,
                               const float* __restrict__ dinv, const float* __restrict__ b2,
                               float* __restrict__ out, int n) {
    int t = threadIdx.x;
    int c2 = t & 3;                       // owns feats 2*c2, 2*c2+1
    int node = blockIdx.x * 64 + (t >> 2);
    if (node >= n) return;
    int start = cursor[node];
    int end = start + degi[node];
    unsigned int su = g2u[node * 4 + c2]; // self-loop init
    float al = bf2f((unsigned short)su),        ah = bf2f((unsigned short)(su >> 16));
    float bl = 0.f, bh = 0.f, cl = 0.f, ch = 0.f, dl = 0.f, dh = 0.f;
    int j = start;
    for (; j + 4 <= end; j += 4) {
        int s0 = srcSorted[j];
        int s1 = srcSorted[j + 1];
        int s2 = srcSorted[j + 2];
        int s3 = srcSorted[j + 3];
        unsigned int u0 = g2u[s0 * 4 + c2];
        unsigned int u1 = g2u[s1 * 4 + c2];
        unsigned int u2 = g2u[s2 * 4 + c2];
        unsigned int u3 = g2u[s3 * 4 + c2];
        al += bf2f((unsigned short)u0); ah += bf2f((unsigned short)(u0 >> 16));
        bl += bf2f((unsigned short)u1); bh += bf2f((unsigned short)(u1 >> 16));
        cl += bf2f((unsigned short)u2); ch += bf2f((unsigned short)(u2 >> 16));
        dl += bf2f((unsigned short)u3); dh += bf2f((unsigned short)(u3 >> 16));
    }
    for (; j < end; ++j) {
        unsigned int u0 = g2u[srcSorted[j] * 4 + c2];
        al += bf2f((unsigned short)u0); ah += bf2f((unsigned short)(u0 >> 16));
    }
    float accl = (al + bl) + (cl + dl);
    float acch = (ah + bh) + (ch + dh);
    float di = dinv[node];
    float vl = di * accl + b2[2 * c2];
    float vh = (c2 < 3) ? (di * acch + b2[2 * c2 + 1]) : -1e30f;  // slot 7 pad
    float m = fmaxf(vl, vh);
    #pragma unroll
    for (int msk = 1; msk < 4; msk <<= 1) m = fmaxf(m, __shfl_xor(m, msk, 64));
    float ssum = __expf(vl - m) + ((c2 < 3) ? __expf(vh - m) : 0.f);
    #pragma unroll
    for (int msk = 1; msk < 4; msk <<= 1) ssum += __shfl_xor(ssum, msk, 64);
    float ls = __logf(ssum) + m;
    __builtin_nontemporal_store(vl - ls, &out[node * F_OUT + 2 * c2]);
    if (c2 < 3) __builtin_nontemporal_store(vh - ls, &out[node * F_OUT + 2 * c2 + 1]);
}

extern "C" void kernel_launch(void* const* d_in, const int* in_sizes, int n_in,
                              void* d_out, int out_size, void* d_ws, size_t ws_size,
                              hipStream_t stream) {
    const float* x  = (const float*)d_in[0];
    const int*   ei = (const int*)d_in[1];
    const float* W1 = (const float*)d_in[2];
    const float* b1 = (const float*)d_in[3];
    const float* W2 = (const float*)d_in[4];
    const float* b2 = (const float*)d_in[5];
    float* out = (float*)d_out;

    int n = in_sizes[0] / F_IN;            // 100000
    int E = in_sizes[1] / 2;               // 3200000
    const int* src = ei;
    const int* dst = ei + E;
    int NB = (n + BNODES - 1) >> BSH;      // 391 buckets
    int NT = (E + TILE - 1) / TILE;        // 391 tiles
    int NSCAN = NB * NT;                   // 152881
    int nsb = (NSCAN + 1023) / 1024;       // 150 scan blocks

    // workspace layout (g1b aliases pairBuf: pairBuf dead after k_bucketCSR)
    int*            degi       = (int*)d_ws;                  // [n]
    int*            cursor     = degi + n;                    // [n]
    float*          dinv       = (float*)(cursor + n);        // [n]
    int*            srcSorted  = (int*)(dinv + n);            // [E]
    int*            pairBuf    = srcSorted + E;               // [E] (reused as g1b)
    unsigned short* g1b        = (unsigned short*)pairBuf;    // [n*32] bf16
    unsigned short* g2b        = (unsigned short*)(pairBuf + E); // [n*8] bf16
    int*            counts     = (int*)(g2b + (size_t)n * 8); // [NSCAN] tile-major
    int*            tileOffset = counts + NSCAN;              // [NSCAN] bucket-major
    int*            bsum       = tileOffset + NSCAN;          // [nsb]
    unsigned short* Wfrag      = (unsigned short*)(bsum + ((nsb + 3) & ~3)); // [4096] bf16

    k_wT<<<1, 256, 0, stream>>>(W1, Wfrag);
    k_tileHist<<<NT, 512, 0, stream>>>(dst, E, NB, counts);
    k_scanA<<<nsb, 1024, 0, stream>>>(counts, NSCAN, NB, NT, bsum);
    k_scanB<<<1, 1024, 0, stream>>>(bsum, nsb);
    k_scanC<<<nsb, 1024, 0, stream>>>(counts, NSCAN, NB, NT, bsum, tileOffset);
    k_tileFill<<<NT, 512, 0, stream>>>(src, dst, E, NB, NT, tileOffset, pairBuf);
    k_bucketCSR<<<NB, 512, 0, stream>>>(pairBuf, tileOffset, NT, NB, E, n,
                                        degi, cursor, dinv, srcSorted);
    k_gemm1<<<(n + 63) / 64, 256, 0, stream>>>(x, Wfrag, dinv, g1b, n);
    k_gather1l2<<<(n + 31) / 32, 256, 0, stream>>>((const ushort4*)g1b, srcSorted, cursor, degi,
                                                   dinv, b1, W2, (unsigned int*)g2b, n);
    k_gather2final<<<(n + 63) / 64, 256, 0, stream>>>((const unsigned int*)g2b, srcSorted, cursor,
                                                      degi, dinv, b2, out, n);
}